// Round 6
// baseline (355.659 us; speedup 1.0000x reference)
//
#include <hip/hip_runtime.h>
#include <hip/hip_bf16.h>
#include <math.h>

#define HIDDEN 1024
#define NH 16
#define HD 64
#define BATCH 2
#define SEQ 2048

typedef __attribute__((ext_vector_type(8))) short bf16x8;
typedef __attribute__((ext_vector_type(4))) float f32x4;

static __device__ __forceinline__ unsigned short f2b(float f) {
    __hip_bfloat16 h = __float2bfloat16(f);
    return __builtin_bit_cast(unsigned short, h);
}
static __device__ __forceinline__ float b2f(unsigned short b) {
    unsigned int u = ((unsigned int)b) << 16;
    return __builtin_bit_cast(float, u);
}

// async global->LDS, 16B per lane. LDS dest must be wave-uniform base + lane*16.
static __device__ __forceinline__ void async16(const unsigned short* g, unsigned short* l) {
    __builtin_amdgcn_global_load_lds(
        (const __attribute__((address_space(1))) unsigned int*)g,
        (__attribute__((address_space(3))) unsigned int*)l, 16, 0, 0);
}

// ---------------------------------------------------------------------------
// Kernel 0: fp32 -> bf16 conversion of X (4M elems) and Wq/Wk/Wv/Wo (1M each).
// ---------------------------------------------------------------------------
__global__ __launch_bounds__(256)
void cvt_bf16(const float* __restrict__ X,
              const float* __restrict__ Wq, const float* __restrict__ Wk,
              const float* __restrict__ Wv, const float* __restrict__ Wo,
              unsigned short* __restrict__ dst)
{
    const size_t g = (size_t)blockIdx.x * 256 + threadIdx.x;  // group of 4 elems
    const float* src;
    size_t local;
    if (g < 1048576) {            // X: 4M elems = 1M groups
        src = X; local = g;
    } else {
        const size_t gg = g - 1048576;
        const int r = (int)(gg >> 18);        // 262144 groups per weight
        local = gg & 262143;
        src = (r == 0) ? Wq : ((r == 1) ? Wk : ((r == 2) ? Wv : Wo));
    }
    const float4 v = *(const float4*)(src + local * 4);
    ushort4 o;
    o.x = f2b(v.x); o.y = f2b(v.y); o.z = f2b(v.z); o.w = f2b(v.w);
    *(ushort4*)(dst + g * 4) = o;
}

// ---------------------------------------------------------------------------
// Kernel 1: fused QKV projection + bias + RoPE (fast __sinf/__cosf path).
// grid (32, 24): y>>3 selects proj (0=q,1=k,2=v), y&7 is the other tile dim.
// Q,K -> (B,NH,S,D), Q pre-scaled by 0.125*log2(e). V -> V^T in (B,NH,D,S).
// ---------------------------------------------------------------------------
__global__ __launch_bounds__(256, 2)
void qkv_rope(const unsigned short* __restrict__ X,
              const unsigned short* __restrict__ Wqb, const float* __restrict__ bq,
              const unsigned short* __restrict__ Wkb, const float* __restrict__ bk,
              const unsigned short* __restrict__ Wvb, const float* __restrict__ bv,
              unsigned short* __restrict__ qw, unsigned short* __restrict__ kw,
              unsigned short* __restrict__ vtw)
{
    const int proj = blockIdx.y >> 3;
    int tm, tn;
    const unsigned short *Amat, *Bmat;
    const float* bias;
    if (proj == 2) {  // V^T: A = Wv (channels), B = X (tokens)
        tm = (blockIdx.y & 7) * 128; tn = blockIdx.x * 128;
        Amat = Wvb; Bmat = X; bias = bv;
    } else {          // Q/K: A = X (tokens), B = W (channels)
        tm = blockIdx.x * 128; tn = (blockIdx.y & 7) * 128;
        Amat = X; Bmat = (proj == 0) ? Wqb : Wkb; bias = (proj == 0) ? bq : bk;
    }

    __shared__ __align__(16) unsigned short As[128 * 32];
    __shared__ __align__(16) unsigned short Bs[128 * 32];

    const int tid  = threadIdx.x;
    const int lane = tid & 63;
    const int wave = tid >> 6;
    const int quad = lane >> 4;
    const int l16  = lane & 15;
    const int wm   = (wave & 1) * 64;
    const int wn   = (wave >> 1) * 64;

    const int r0 = tid >> 2;
    const int c0 = (tid & 3) * 8;
    const unsigned short* Ag = Amat + (size_t)(tm + r0) * HIDDEN + c0;
    const unsigned short* Bg = Bmat + (size_t)(tn + r0) * HIDDEN + c0;
    unsigned short* lA = As + tid * 8;
    unsigned short* lB = Bs + tid * 8;

    f32x4 acc[4][4] = {};

    for (int k0 = 0; k0 < HIDDEN; k0 += 32) {
        __syncthreads();
        async16(Ag + k0, lA);
        async16(Ag + 64 * HIDDEN + k0, lA + 2048);
        async16(Bg + k0, lB);
        async16(Bg + 64 * HIDDEN + k0, lB + 2048);
        __syncthreads();
        bf16x8 af[4], bfr[4];
#pragma unroll
        for (int i = 0; i < 4; ++i)
            af[i] = *(const bf16x8*)(As + (wm + i * 16 + l16) * 32 + quad * 8);
#pragma unroll
        for (int j = 0; j < 4; ++j)
            bfr[j] = *(const bf16x8*)(Bs + (wn + j * 16 + l16) * 32 + quad * 8);
#pragma unroll
        for (int i = 0; i < 4; ++i)
#pragma unroll
            for (int j = 0; j < 4; ++j)
                acc[i][j] = __builtin_amdgcn_mfma_f32_16x16x32_bf16(af[i], bfr[j], acc[i][j], 0, 0, 0);
    }

    if (proj == 2) {
        // C[m=channel][n=token] = V^T. Store (B,NH,D,S).
#pragma unroll
        for (int i = 0; i < 4; ++i) {
#pragma unroll
            for (int r = 0; r < 4; ++r) {
                const int m = tm + wm + i * 16 + quad * 4 + r;  // channel
                const int hh = m >> 6, d = m & 63;
                const float bb = bias[m];
#pragma unroll
                for (int j = 0; j < 4; ++j) {
                    const int n = tn + wn + j * 16 + l16;       // token
                    const int bb2 = n >> 11, s = n & (SEQ - 1);
                    vtw[(((size_t)(bb2 * NH + hh)) * HD + d) * SEQ + s] = f2b(acc[i][j][r] + bb);
                }
            }
        }
        return;
    }

    // Q/K epilogue: bias + RoPE (+ Q pre-scale) + store (B,NH,S,D).
    unsigned short* outp = (proj == 0) ? qw : kw;
    const float qscale = (proj == 0) ? 0.18033688011f : 1.0f;  // 0.125*log2(e)
    float bsv[4];
#pragma unroll
    for (int j = 0; j < 4; ++j) bsv[j] = bias[tn + wn + j * 16 + l16];
    // inv freq: 10000^(-idx/32) = exp2(-idx * log2(10000)/32), log2(1e4)/32=0.41524101
    const float inv_e = exp2f(-0.41524101186f * (float)l16);
    const float inv_o = exp2f(-0.41524101186f * (float)(16 + l16));
#pragma unroll
    for (int i = 0; i < 4; ++i) {
#pragma unroll
        for (int r = 0; r < 4; ++r) {
            const int m = tm + wm + i * 16 + quad * 4 + r;  // C/D row = quad*4+r
            const int b = m >> 11;
            const int s = m & (SEQ - 1);
            const float sf = (float)s;
            const float a0 = sf * inv_e, a1 = sf * inv_o;
            const float cs0 = __cosf(a0), sn0 = __sinf(a0);
            const float cs1 = __cosf(a1), sn1 = __sinf(a1);
#pragma unroll
            for (int j = 0; j < 4; ++j) {
                const int n = tn + wn + j * 16 + l16;       // C/D col = lane&15
                const float v  = acc[i][j][r] + bsv[j];
                const float vp = acc[i][j ^ 2][r] + bsv[j ^ 2];
                const float o = (v * ((j & 1) ? cs1 : cs0)
                                 + ((j < 2) ? -vp : vp) * ((j & 1) ? sn1 : sn0)) * qscale;
                const int h = n >> 6;
                const int d = n & 63;
                outp[(((size_t)(b * NH + h)) * SEQ + s) * HD + d] = f2b(o);
            }
        }
    }
}

// ---------------------------------------------------------------------------
// Kernel 2: flash attention v4 — zero barriers + SPLIT-K (2 key-halves).
// grid (32 bh, 16 q-tiles, 2 splits): linear id ≡ bh (mod 8) -> all blocks of
// one bh land on one XCD (K/V L2-resident: 4 bh x 512 KB = 2 MB/XCD).
// Block 256 = 4 independent waves x 32 q-rows; 4 blocks/CU (50% occupancy).
// Writes UNNORMALIZED O partial (bf16, (B,S,H) layout) + l partial per split.
// ---------------------------------------------------------------------------
__global__ __launch_bounds__(256, 4)
void attn_fwd(const unsigned short* __restrict__ qb, const unsigned short* __restrict__ kb,
              const unsigned short* __restrict__ vtb,
              unsigned short* __restrict__ p0, unsigned short* __restrict__ p1,
              float* __restrict__ l0, float* __restrict__ l1)
{
    const int bh = blockIdx.x;
    const int z  = blockIdx.z;
    const int b  = bh >> 4;
    const int h  = bh & 15;
    const unsigned short* Q  = qb  + (size_t)bh * SEQ * HD;
    const unsigned short* K  = kb  + (size_t)bh * SEQ * HD;
    const unsigned short* VT = vtb + (size_t)bh * HD * SEQ;
    unsigned short* op = z ? p1 : p0;
    float*          lp = z ? l1 : l0;

    const int tid  = threadIdx.x;
    const int wave = tid >> 6;
    const int lane = tid & 63;
    const int quad = lane >> 4;
    const int l16  = lane & 15;
    const int q0   = blockIdx.y * 128 + wave * 32;

    __shared__ __align__(16) unsigned short Pb[4][32 * 136];  // per-wave P [qrow][key]

    // Q fragments (A operand), held in registers for all K tiles
    bf16x8 qf[2][2];
#pragma unroll
    for (int mt = 0; mt < 2; ++mt)
#pragma unroll
        for (int kk = 0; kk < 2; ++kk)
            qf[mt][kk] = *(const bf16x8*)(Q + (size_t)(q0 + mt * 16 + l16) * HD + kk * 32 + quad * 8);

    f32x4 oacc[2][4] = {};
    float lsum[2][4] = {};

    for (int kt = z * 8; kt < z * 8 + 8; ++kt) {
        const int t0 = kt * 128;

        // S = Q K^T  (K B-operand fragments straight from global)
        f32x4 sc[2][8] = {};
#pragma unroll
        for (int kk = 0; kk < 2; ++kk) {
            bf16x8 kf[8];
#pragma unroll
            for (int jj = 0; jj < 8; ++jj)
                kf[jj] = *(const bf16x8*)(K + (size_t)(t0 + jj * 16 + l16) * HD + kk * 32 + quad * 8);
#pragma unroll
            for (int mt = 0; mt < 2; ++mt)
#pragma unroll
                for (int jj = 0; jj < 8; ++jj)
                    sc[mt][jj] = __builtin_amdgcn_mfma_f32_16x16x32_bf16(qf[mt][kk], kf[jj], sc[mt][jj], 0, 0, 0);
        }

        // P = exp2(S) (scale pre-folded into Q), partial row sums, P -> LDS
#pragma unroll
        for (int mt = 0; mt < 2; ++mt) {
#pragma unroll
            for (int r = 0; r < 4; ++r) {
                const int prow = (mt * 16 + quad * 4 + r) * 136;
                float ps = 0.f;
#pragma unroll
                for (int jj = 0; jj < 8; ++jj) {
                    const float p = exp2f(sc[mt][jj][r]);
                    ps += p;
                    Pb[wave][prow + jj * 16 + l16] = f2b(p);
                }
                lsum[mt][r] += ps;
            }
        }

        // O += P V  (A = P from wave-private LDS, B = V^T from global)
#pragma unroll
        for (int kk2 = 0; kk2 < 4; ++kk2) {
            bf16x8 pf[2], vf[4];
#pragma unroll
            for (int mt = 0; mt < 2; ++mt)
                pf[mt] = *(const bf16x8*)(&Pb[wave][(mt * 16 + l16) * 136 + kk2 * 32 + quad * 8]);
#pragma unroll
            for (int nn = 0; nn < 4; ++nn)
                vf[nn] = *(const bf16x8*)(VT + (size_t)(nn * 16 + l16) * SEQ + t0 + kk2 * 32 + quad * 8);
#pragma unroll
            for (int mt = 0; mt < 2; ++mt)
#pragma unroll
                for (int nn = 0; nn < 4; ++nn)
                    oacc[mt][nn] = __builtin_amdgcn_mfma_f32_16x16x32_bf16(pf[mt], vf[nn], oacc[mt][nn], 0, 0, 0);
        }
    }

    // store UNNORMALIZED O partial (B,S,H layout) + per-row l partial
#pragma unroll
    for (int mt = 0; mt < 2; ++mt) {
#pragma unroll
        for (int r = 0; r < 4; ++r) {
            float l = lsum[mt][r];
#pragma unroll
            for (int off = 8; off; off >>= 1) l += __shfl_xor(l, off);
            const int s = q0 + mt * 16 + quad * 4 + r;
            if (l16 == 0) lp[bh * SEQ + s] = l;
#pragma unroll
            for (int nn = 0; nn < 4; ++nn) {
                const int d = nn * 16 + l16;
                op[((size_t)(b * SEQ + s)) * HIDDEN + h * HD + d] = f2b(oacc[mt][nn][r]);
            }
        }
    }
}

// ---------------------------------------------------------------------------
// Kernel 2b: merge the two split-K partials: aw = (O0 + O1) / (l0 + l1).
// p0 occupies the aw region; in-place same-index RMW (no permutation -> safe).
// 8 elems/thread. grid 2048 x 256.
// ---------------------------------------------------------------------------
__global__ __launch_bounds__(256)
void merge_norm(unsigned short* __restrict__ p0, const unsigned short* __restrict__ p1,
                const float* __restrict__ l0, const float* __restrict__ l1)
{
    const size_t t = (size_t)blockIdx.x * 256 + threadIdx.x;
    const size_t e = t * 8;                       // first of 8 contiguous elems
    const int b = (int)(e >> 21);                 // S*HIDDEN = 2^21 per batch
    const int s = (int)((e >> 10) & (SEQ - 1));
    const int h = (int)((e >> 6) & (NH - 1));
    const float inv = 1.0f / (l0[(b * NH + h) * SEQ + s] + l1[(b * NH + h) * SEQ + s]);
    ushort4 a0 = *(const ushort4*)(p0 + e);
    ushort4 a1 = *(const ushort4*)(p0 + e + 4);
    ushort4 c0 = *(const ushort4*)(p1 + e);
    ushort4 c1 = *(const ushort4*)(p1 + e + 4);
    ushort4 o0, o1;
    o0.x = f2b((b2f(a0.x) + b2f(c0.x)) * inv);
    o0.y = f2b((b2f(a0.y) + b2f(c0.y)) * inv);
    o0.z = f2b((b2f(a0.z) + b2f(c0.z)) * inv);
    o0.w = f2b((b2f(a0.w) + b2f(c0.w)) * inv);
    o1.x = f2b((b2f(a1.x) + b2f(c1.x)) * inv);
    o1.y = f2b((b2f(a1.y) + b2f(c1.y)) * inv);
    o1.z = f2b((b2f(a1.z) + b2f(c1.z)) * inv);
    o1.w = f2b((b2f(a1.w) + b2f(c1.w)) * inv);
    *(ushort4*)(p0 + e)     = o0;
    *(ushort4*)(p0 + e + 4) = o1;
}

// ---------------------------------------------------------------------------
// Kernel 3: output projection GEMM + fp32 bias. grid (32, 8). Output FP32.
// ---------------------------------------------------------------------------
__global__ __launch_bounds__(256, 2)
void out_proj(const unsigned short* __restrict__ A,
              const unsigned short* __restrict__ W,
              const float* __restrict__ bias,
              float* __restrict__ out)
{
    const int tn = blockIdx.y * 128;
    const int tm = blockIdx.x * 128;

    __shared__ __align__(16) unsigned short As[128 * 32];
    __shared__ __align__(16) unsigned short Bs[128 * 32];

    const int tid  = threadIdx.x;
    const int lane = tid & 63;
    const int wave = tid >> 6;
    const int quad = lane >> 4;
    const int l16  = lane & 15;
    const int wm   = (wave & 1) * 64;
    const int wn   = (wave >> 1) * 64;

    const int r0 = tid >> 2;
    const int c0 = (tid & 3) * 8;
    const unsigned short* Ag = A + (size_t)(tm + r0) * HIDDEN + c0;
    const unsigned short* Bg = W + (size_t)(tn + r0) * HIDDEN + c0;
    unsigned short* lA = As + tid * 8;
    unsigned short* lB = Bs + tid * 8;

    f32x4 acc[4][4] = {};

    for (int k0 = 0; k0 < HIDDEN; k0 += 32) {
        __syncthreads();
        async16(Ag + k0, lA);
        async16(Ag + 64 * HIDDEN + k0, lA + 2048);
        async16(Bg + k0, lB);
        async16(Bg + 64 * HIDDEN + k0, lB + 2048);
        __syncthreads();
        bf16x8 af[4], bfr[4];
#pragma unroll
        for (int i = 0; i < 4; ++i)
            af[i] = *(const bf16x8*)(As + (wm + i * 16 + l16) * 32 + quad * 8);
#pragma unroll
        for (int j = 0; j < 4; ++j)
            bfr[j] = *(const bf16x8*)(Bs + (wn + j * 16 + l16) * 32 + quad * 8);
#pragma unroll
        for (int i = 0; i < 4; ++i)
#pragma unroll
            for (int j = 0; j < 4; ++j)
                acc[i][j] = __builtin_amdgcn_mfma_f32_16x16x32_bf16(af[i], bfr[j], acc[i][j], 0, 0, 0);
    }

    float bsv[4];
#pragma unroll
    for (int j = 0; j < 4; ++j) bsv[j] = bias[tn + wn + j * 16 + l16];
#pragma unroll
    for (int i = 0; i < 4; ++i) {
#pragma unroll
        for (int r = 0; r < 4; ++r) {
            const int m = tm + wm + i * 16 + quad * 4 + r;
#pragma unroll
            for (int j = 0; j < 4; ++j) {
                const int n = tn + wn + j * 16 + l16;
                out[(size_t)m * HIDDEN + n] = acc[i][j][r] + bsv[j];   // fp32 output
            }
        }
    }
}

extern "C" void kernel_launch(void* const* d_in, const int* in_sizes, int n_in,
                              void* d_out, int out_size, void* d_ws, size_t ws_size,
                              hipStream_t stream) {
    const float* hs = (const float*)d_in[0];
    const float* Wq = (const float*)d_in[1];
    const float* bq = (const float*)d_in[2];
    const float* Wk = (const float*)d_in[3];
    const float* bk = (const float*)d_in[4];
    const float* Wv = (const float*)d_in[5];
    const float* bv = (const float*)d_in[6];
    const float* Wo = (const float*)d_in[7];
    const float* bo = (const float*)d_in[8];
    float* out = (float*)d_out;

    // ws layout (bf16 elem offsets), 48 MB total — regions are REUSED:
    //   [0,4M)      Xb   (X bf16)           -> dead after qkv_rope -> attn p1
    //   [4M,4.5M+)  Wqb  (2 MB region)      -> dead after qkv_rope -> l0,l1 (512 KB)
    //   [5M,6M)     Wkb, [6M,7M) Wvb        -> dead after qkv_rope
    //   [7M,8M)     Wob                     -> live until out_proj
    //   [8M,12M)    qw   [12M,16M) kw   [16M,20M) vtw
    //   [20M,24M)   aw region = attn p0 -> merge_norm normalizes in-place
    unsigned short* Xb  = (unsigned short*)d_ws;
    unsigned short* Wqb = Xb + 4194304;
    unsigned short* Wkb = Wqb + 1048576;
    unsigned short* Wvb = Wkb + 1048576;
    unsigned short* Wob = Wvb + 1048576;
    unsigned short* qw  = Wob + 1048576;
    unsigned short* kw  = qw + 4194304;
    unsigned short* vtw = kw + 4194304;   // V^T: (B,NH,D,S)
    unsigned short* aw  = vtw + 4194304;  // p0 / final attention output (B,S,H)

    unsigned short* p1 = Xb;              // split-1 partial, (B,S,H) bf16
    float* l0 = (float*)Wqb;              // 65536 floats
    float* l1 = l0 + BATCH * NH * SEQ;    // 65536 floats

    cvt_bf16<<<dim3(8192), 256, 0, stream>>>(hs, Wq, Wk, Wv, Wo, Xb);
    qkv_rope<<<dim3(32, 24), 256, 0, stream>>>(Xb, Wqb, bq, Wkb, bk, Wvb, bv, qw, kw, vtw);
    attn_fwd<<<dim3(32, 16, 2), 256, 0, stream>>>(qw, kw, vtw, aw, p1, l0, l1);
    merge_norm<<<dim3(2048), 256, 0, stream>>>(aw, p1, l0, l1);
    out_proj<<<dim3(32, 8), 256, 0, stream>>>(aw, Wob, bo, out);
}

// Round 7
// 279.866 us; speedup vs baseline: 1.2708x; 1.2708x over previous
//
#include <hip/hip_runtime.h>
#include <hip/hip_bf16.h>
#include <math.h>

#define HIDDEN 1024
#define NH 16
#define HD 64
#define BATCH 2
#define SEQ 2048

typedef __attribute__((ext_vector_type(8))) short bf16x8;
typedef __attribute__((ext_vector_type(4))) float f32x4;

static __device__ __forceinline__ unsigned short f2b(float f) {
    __hip_bfloat16 h = __float2bfloat16(f);
    return __builtin_bit_cast(unsigned short, h);
}
static __device__ __forceinline__ float b2f(unsigned short b) {
    unsigned int u = ((unsigned int)b) << 16;
    return __builtin_bit_cast(float, u);
}

// async global->LDS, 16B per lane. LDS dest must be wave-uniform base + lane*16.
static __device__ __forceinline__ void async16(const unsigned short* g, unsigned short* l) {
    __builtin_amdgcn_global_load_lds(
        (const __attribute__((address_space(1))) unsigned int*)g,
        (__attribute__((address_space(3))) unsigned int*)l, 16, 0, 0);
}

// ---------------------------------------------------------------------------
// Kernel 0: fp32 -> bf16 conversion of X (4M elems) and Wq/Wk/Wv/Wo (1M each).
// ---------------------------------------------------------------------------
__global__ __launch_bounds__(256)
void cvt_bf16(const float* __restrict__ X,
              const float* __restrict__ Wq, const float* __restrict__ Wk,
              const float* __restrict__ Wv, const float* __restrict__ Wo,
              unsigned short* __restrict__ dst)
{
    const size_t g = (size_t)blockIdx.x * 256 + threadIdx.x;  // group of 4 elems
    const float* src;
    size_t local;
    if (g < 1048576) {            // X: 4M elems = 1M groups
        src = X; local = g;
    } else {
        const size_t gg = g - 1048576;
        const int r = (int)(gg >> 18);        // 262144 groups per weight
        local = gg & 262143;
        src = (r == 0) ? Wq : ((r == 1) ? Wk : ((r == 2) ? Wv : Wo));
    }
    const float4 v = *(const float4*)(src + local * 4);
    ushort4 o;
    o.x = f2b(v.x); o.y = f2b(v.y); o.z = f2b(v.z); o.w = f2b(v.w);
    *(ushort4*)(dst + g * 4) = o;
}

// ---------------------------------------------------------------------------
// Kernel 1: fused QKV projection + bias + RoPE (fast __sinf/__cosf path).
// grid (32, 24): y>>3 selects proj (0=q,1=k,2=v), y&7 is the other tile dim.
// Q,K -> (B,NH,S,D), Q pre-scaled by 0.125*log2(e). V -> V^T in (B,NH,D,S).
// ---------------------------------------------------------------------------
__global__ __launch_bounds__(256, 2)
void qkv_rope(const unsigned short* __restrict__ X,
              const unsigned short* __restrict__ Wqb, const float* __restrict__ bq,
              const unsigned short* __restrict__ Wkb, const float* __restrict__ bk,
              const unsigned short* __restrict__ Wvb, const float* __restrict__ bv,
              unsigned short* __restrict__ qw, unsigned short* __restrict__ kw,
              unsigned short* __restrict__ vtw)
{
    const int proj = blockIdx.y >> 3;
    int tm, tn;
    const unsigned short *Amat, *Bmat;
    const float* bias;
    if (proj == 2) {  // V^T: A = Wv (channels), B = X (tokens)
        tm = (blockIdx.y & 7) * 128; tn = blockIdx.x * 128;
        Amat = Wvb; Bmat = X; bias = bv;
    } else {          // Q/K: A = X (tokens), B = W (channels)
        tm = blockIdx.x * 128; tn = (blockIdx.y & 7) * 128;
        Amat = X; Bmat = (proj == 0) ? Wqb : Wkb; bias = (proj == 0) ? bq : bk;
    }

    __shared__ __align__(16) unsigned short As[128 * 32];
    __shared__ __align__(16) unsigned short Bs[128 * 32];

    const int tid  = threadIdx.x;
    const int lane = tid & 63;
    const int wave = tid >> 6;
    const int quad = lane >> 4;
    const int l16  = lane & 15;
    const int wm   = (wave & 1) * 64;
    const int wn   = (wave >> 1) * 64;

    const int r0 = tid >> 2;
    const int c0 = (tid & 3) * 8;
    const unsigned short* Ag = Amat + (size_t)(tm + r0) * HIDDEN + c0;
    const unsigned short* Bg = Bmat + (size_t)(tn + r0) * HIDDEN + c0;
    unsigned short* lA = As + tid * 8;
    unsigned short* lB = Bs + tid * 8;

    f32x4 acc[4][4] = {};

    for (int k0 = 0; k0 < HIDDEN; k0 += 32) {
        __syncthreads();
        async16(Ag + k0, lA);
        async16(Ag + 64 * HIDDEN + k0, lA + 2048);
        async16(Bg + k0, lB);
        async16(Bg + 64 * HIDDEN + k0, lB + 2048);
        __syncthreads();
        bf16x8 af[4], bfr[4];
#pragma unroll
        for (int i = 0; i < 4; ++i)
            af[i] = *(const bf16x8*)(As + (wm + i * 16 + l16) * 32 + quad * 8);
#pragma unroll
        for (int j = 0; j < 4; ++j)
            bfr[j] = *(const bf16x8*)(Bs + (wn + j * 16 + l16) * 32 + quad * 8);
#pragma unroll
        for (int i = 0; i < 4; ++i)
#pragma unroll
            for (int j = 0; j < 4; ++j)
                acc[i][j] = __builtin_amdgcn_mfma_f32_16x16x32_bf16(af[i], bfr[j], acc[i][j], 0, 0, 0);
    }

    if (proj == 2) {
        // C[m=channel][n=token] = V^T. Store (B,NH,D,S).
#pragma unroll
        for (int i = 0; i < 4; ++i) {
#pragma unroll
            for (int r = 0; r < 4; ++r) {
                const int m = tm + wm + i * 16 + quad * 4 + r;  // channel
                const int hh = m >> 6, d = m & 63;
                const float bb = bias[m];
#pragma unroll
                for (int j = 0; j < 4; ++j) {
                    const int n = tn + wn + j * 16 + l16;       // token
                    const int bb2 = n >> 11, s = n & (SEQ - 1);
                    vtw[(((size_t)(bb2 * NH + hh)) * HD + d) * SEQ + s] = f2b(acc[i][j][r] + bb);
                }
            }
        }
        return;
    }

    // Q/K epilogue: bias + RoPE (+ Q pre-scale) + store (B,NH,S,D).
    unsigned short* outp = (proj == 0) ? qw : kw;
    const float qscale = (proj == 0) ? 0.18033688011f : 1.0f;  // 0.125*log2(e)
    float bsv[4];
#pragma unroll
    for (int j = 0; j < 4; ++j) bsv[j] = bias[tn + wn + j * 16 + l16];
    // inv freq: 10000^(-idx/32) = exp2(-idx * log2(10000)/32), log2(1e4)/32=0.41524101
    const float inv_e = exp2f(-0.41524101186f * (float)l16);
    const float inv_o = exp2f(-0.41524101186f * (float)(16 + l16));
#pragma unroll
    for (int i = 0; i < 4; ++i) {
#pragma unroll
        for (int r = 0; r < 4; ++r) {
            const int m = tm + wm + i * 16 + quad * 4 + r;  // C/D row = quad*4+r
            const int b = m >> 11;
            const int s = m & (SEQ - 1);
            const float sf = (float)s;
            const float a0 = sf * inv_e, a1 = sf * inv_o;
            const float cs0 = __cosf(a0), sn0 = __sinf(a0);
            const float cs1 = __cosf(a1), sn1 = __sinf(a1);
#pragma unroll
            for (int j = 0; j < 4; ++j) {
                const int n = tn + wn + j * 16 + l16;       // C/D col = lane&15
                const float v  = acc[i][j][r] + bsv[j];
                const float vp = acc[i][j ^ 2][r] + bsv[j ^ 2];
                const float o = (v * ((j & 1) ? cs1 : cs0)
                                 + ((j < 2) ? -vp : vp) * ((j & 1) ? sn1 : sn0)) * qscale;
                const int h = n >> 6;
                const int d = n & 63;
                outp[(((size_t)(b * NH + h)) * SEQ + s) * HD + d] = f2b(o);
            }
        }
    }
}

// ---------------------------------------------------------------------------
// Kernel 2: flash attention v5 — zero barriers + split-K (2 key-halves).
// grid (32 bh, 16 q-tiles, 2 splits), block 256 = 4 independent waves x 32
// q-rows. __launch_bounds__(256,2): r6 showed (256,4) caps VGPR at 64 and the
// M=32 body (sc[2][8]=64 regs + oacc 32 + qf 8) spills to scratch -> 500 MB
// of HBM spill traffic. (256,2) gives the allocator ~92-124 regs (r3/r5),
// which still allows 4 blocks/CU at 4 waves/EU (<=128 VGPR) with LDS 34.8 KB.
// Writes UNNORMALIZED O partial (bf16, (B,S,H)) + l partial per split.
// ---------------------------------------------------------------------------
__global__ __launch_bounds__(256, 2)
void attn_fwd(const unsigned short* __restrict__ qb, const unsigned short* __restrict__ kb,
              const unsigned short* __restrict__ vtb,
              unsigned short* __restrict__ p0, unsigned short* __restrict__ p1,
              float* __restrict__ l0, float* __restrict__ l1)
{
    const int bh = blockIdx.x;
    const int z  = blockIdx.z;
    const int b  = bh >> 4;
    const int h  = bh & 15;
    const unsigned short* Q  = qb  + (size_t)bh * SEQ * HD;
    const unsigned short* K  = kb  + (size_t)bh * SEQ * HD;
    const unsigned short* VT = vtb + (size_t)bh * HD * SEQ;
    unsigned short* op = z ? p1 : p0;
    float*          lp = z ? l1 : l0;

    const int tid  = threadIdx.x;
    const int wave = tid >> 6;
    const int lane = tid & 63;
    const int quad = lane >> 4;
    const int l16  = lane & 15;
    const int q0   = blockIdx.y * 128 + wave * 32;

    __shared__ __align__(16) unsigned short Pb[4][32 * 136];  // per-wave P [qrow][key]

    // Q fragments (A operand), held in registers for all K tiles
    bf16x8 qf[2][2];
#pragma unroll
    for (int mt = 0; mt < 2; ++mt)
#pragma unroll
        for (int kk = 0; kk < 2; ++kk)
            qf[mt][kk] = *(const bf16x8*)(Q + (size_t)(q0 + mt * 16 + l16) * HD + kk * 32 + quad * 8);

    f32x4 oacc[2][4] = {};
    float lsum[2][4] = {};

    for (int kt = z * 8; kt < z * 8 + 8; ++kt) {
        const int t0 = kt * 128;

        // S = Q K^T  (K B-operand fragments straight from global)
        f32x4 sc[2][8] = {};
#pragma unroll
        for (int kk = 0; kk < 2; ++kk) {
            bf16x8 kf[8];
#pragma unroll
            for (int jj = 0; jj < 8; ++jj)
                kf[jj] = *(const bf16x8*)(K + (size_t)(t0 + jj * 16 + l16) * HD + kk * 32 + quad * 8);
#pragma unroll
            for (int mt = 0; mt < 2; ++mt)
#pragma unroll
                for (int jj = 0; jj < 8; ++jj)
                    sc[mt][jj] = __builtin_amdgcn_mfma_f32_16x16x32_bf16(qf[mt][kk], kf[jj], sc[mt][jj], 0, 0, 0);
        }

        // P = exp2(S) (scale pre-folded into Q), partial row sums, P -> LDS
#pragma unroll
        for (int mt = 0; mt < 2; ++mt) {
#pragma unroll
            for (int r = 0; r < 4; ++r) {
                const int prow = (mt * 16 + quad * 4 + r) * 136;
                float ps = 0.f;
#pragma unroll
                for (int jj = 0; jj < 8; ++jj) {
                    const float p = exp2f(sc[mt][jj][r]);
                    ps += p;
                    Pb[wave][prow + jj * 16 + l16] = f2b(p);
                }
                lsum[mt][r] += ps;
            }
        }

        // O += P V  (A = P from wave-private LDS, B = V^T from global)
#pragma unroll
        for (int kk2 = 0; kk2 < 4; ++kk2) {
            bf16x8 pf[2], vf[4];
#pragma unroll
            for (int mt = 0; mt < 2; ++mt)
                pf[mt] = *(const bf16x8*)(&Pb[wave][(mt * 16 + l16) * 136 + kk2 * 32 + quad * 8]);
#pragma unroll
            for (int nn = 0; nn < 4; ++nn)
                vf[nn] = *(const bf16x8*)(VT + (size_t)(nn * 16 + l16) * SEQ + t0 + kk2 * 32 + quad * 8);
#pragma unroll
            for (int mt = 0; mt < 2; ++mt)
#pragma unroll
                for (int nn = 0; nn < 4; ++nn)
                    oacc[mt][nn] = __builtin_amdgcn_mfma_f32_16x16x32_bf16(pf[mt], vf[nn], oacc[mt][nn], 0, 0, 0);
        }
    }

    // store UNNORMALIZED O partial (B,S,H layout) + per-row l partial
#pragma unroll
    for (int mt = 0; mt < 2; ++mt) {
#pragma unroll
        for (int r = 0; r < 4; ++r) {
            float l = lsum[mt][r];
#pragma unroll
            for (int off = 8; off; off >>= 1) l += __shfl_xor(l, off);
            const int s = q0 + mt * 16 + quad * 4 + r;
            if (l16 == 0) lp[bh * SEQ + s] = l;
#pragma unroll
            for (int nn = 0; nn < 4; ++nn) {
                const int d = nn * 16 + l16;
                op[((size_t)(b * SEQ + s)) * HIDDEN + h * HD + d] = f2b(oacc[mt][nn][r]);
            }
        }
    }
}

// ---------------------------------------------------------------------------
// Kernel 2b: merge the two split-K partials: aw = (O0 + O1) / (l0 + l1).
// p0 occupies the aw region; in-place same-index RMW (no permutation -> safe).
// 8 elems/thread. grid 2048 x 256.
// ---------------------------------------------------------------------------
__global__ __launch_bounds__(256)
void merge_norm(unsigned short* __restrict__ p0, const unsigned short* __restrict__ p1,
                const float* __restrict__ l0, const float* __restrict__ l1)
{
    const size_t t = (size_t)blockIdx.x * 256 + threadIdx.x;
    const size_t e = t * 8;                       // first of 8 contiguous elems
    const int b = (int)(e >> 21);                 // S*HIDDEN = 2^21 per batch
    const int s = (int)((e >> 10) & (SEQ - 1));
    const int h = (int)((e >> 6) & (NH - 1));
    const float inv = 1.0f / (l0[(b * NH + h) * SEQ + s] + l1[(b * NH + h) * SEQ + s]);
    ushort4 a0 = *(const ushort4*)(p0 + e);
    ushort4 a1 = *(const ushort4*)(p0 + e + 4);
    ushort4 c0 = *(const ushort4*)(p1 + e);
    ushort4 c1 = *(const ushort4*)(p1 + e + 4);
    ushort4 o0, o1;
    o0.x = f2b((b2f(a0.x) + b2f(c0.x)) * inv);
    o0.y = f2b((b2f(a0.y) + b2f(c0.y)) * inv);
    o0.z = f2b((b2f(a0.z) + b2f(c0.z)) * inv);
    o0.w = f2b((b2f(a0.w) + b2f(c0.w)) * inv);
    o1.x = f2b((b2f(a1.x) + b2f(c1.x)) * inv);
    o1.y = f2b((b2f(a1.y) + b2f(c1.y)) * inv);
    o1.z = f2b((b2f(a1.z) + b2f(c1.z)) * inv);
    o1.w = f2b((b2f(a1.w) + b2f(c1.w)) * inv);
    *(ushort4*)(p0 + e)     = o0;
    *(ushort4*)(p0 + e + 4) = o1;
}

// ---------------------------------------------------------------------------
// Kernel 3: output projection GEMM + fp32 bias. grid (32, 8). Output FP32.
// ---------------------------------------------------------------------------
__global__ __launch_bounds__(256, 2)
void out_proj(const unsigned short* __restrict__ A,
              const unsigned short* __restrict__ W,
              const float* __restrict__ bias,
              float* __restrict__ out)
{
    const int tn = blockIdx.y * 128;
    const int tm = blockIdx.x * 128;

    __shared__ __align__(16) unsigned short As[128 * 32];
    __shared__ __align__(16) unsigned short Bs[128 * 32];

    const int tid  = threadIdx.x;
    const int lane = tid & 63;
    const int wave = tid >> 6;
    const int quad = lane >> 4;
    const int l16  = lane & 15;
    const int wm   = (wave & 1) * 64;
    const int wn   = (wave >> 1) * 64;

    const int r0 = tid >> 2;
    const int c0 = (tid & 3) * 8;
    const unsigned short* Ag = A + (size_t)(tm + r0) * HIDDEN + c0;
    const unsigned short* Bg = W + (size_t)(tn + r0) * HIDDEN + c0;
    unsigned short* lA = As + tid * 8;
    unsigned short* lB = Bs + tid * 8;

    f32x4 acc[4][4] = {};

    for (int k0 = 0; k0 < HIDDEN; k0 += 32) {
        __syncthreads();
        async16(Ag + k0, lA);
        async16(Ag + 64 * HIDDEN + k0, lA + 2048);
        async16(Bg + k0, lB);
        async16(Bg + 64 * HIDDEN + k0, lB + 2048);
        __syncthreads();
        bf16x8 af[4], bfr[4];
#pragma unroll
        for (int i = 0; i < 4; ++i)
            af[i] = *(const bf16x8*)(As + (wm + i * 16 + l16) * 32 + quad * 8);
#pragma unroll
        for (int j = 0; j < 4; ++j)
            bfr[j] = *(const bf16x8*)(Bs + (wn + j * 16 + l16) * 32 + quad * 8);
#pragma unroll
        for (int i = 0; i < 4; ++i)
#pragma unroll
            for (int j = 0; j < 4; ++j)
                acc[i][j] = __builtin_amdgcn_mfma_f32_16x16x32_bf16(af[i], bfr[j], acc[i][j], 0, 0, 0);
    }

    float bsv[4];
#pragma unroll
    for (int j = 0; j < 4; ++j) bsv[j] = bias[tn + wn + j * 16 + l16];
#pragma unroll
    for (int i = 0; i < 4; ++i) {
#pragma unroll
        for (int r = 0; r < 4; ++r) {
            const int m = tm + wm + i * 16 + quad * 4 + r;
#pragma unroll
            for (int j = 0; j < 4; ++j) {
                const int n = tn + wn + j * 16 + l16;
                out[(size_t)m * HIDDEN + n] = acc[i][j][r] + bsv[j];   // fp32 output
            }
        }
    }
}

extern "C" void kernel_launch(void* const* d_in, const int* in_sizes, int n_in,
                              void* d_out, int out_size, void* d_ws, size_t ws_size,
                              hipStream_t stream) {
    const float* hs = (const float*)d_in[0];
    const float* Wq = (const float*)d_in[1];
    const float* bq = (const float*)d_in[2];
    const float* Wk = (const float*)d_in[3];
    const float* bk = (const float*)d_in[4];
    const float* Wv = (const float*)d_in[5];
    const float* bv = (const float*)d_in[6];
    const float* Wo = (const float*)d_in[7];
    const float* bo = (const float*)d_in[8];
    float* out = (float*)d_out;

    // ws layout (bf16 elem offsets), 48 MB total — regions are REUSED:
    //   [0,4M)      Xb   (X bf16)           -> dead after qkv_rope -> attn p1
    //   [4M,4.5M)   Wqb region              -> dead after qkv_rope -> l0,l1
    //   [5M,6M)     Wkb, [6M,7M) Wvb        -> dead after qkv_rope
    //   [7M,8M)     Wob                     -> live until out_proj
    //   [8M,12M)    qw   [12M,16M) kw   [16M,20M) vtw
    //   [20M,24M)   aw region = attn p0 -> merge_norm normalizes in-place
    unsigned short* Xb  = (unsigned short*)d_ws;
    unsigned short* Wqb = Xb + 4194304;
    unsigned short* Wkb = Wqb + 1048576;
    unsigned short* Wvb = Wkb + 1048576;
    unsigned short* Wob = Wvb + 1048576;
    unsigned short* qw  = Wob + 1048576;
    unsigned short* kw  = qw + 4194304;
    unsigned short* vtw = kw + 4194304;   // V^T: (B,NH,D,S)
    unsigned short* aw  = vtw + 4194304;  // p0 / final attention output (B,S,H)

    unsigned short* p1 = Xb;              // split-1 partial, (B,S,H) bf16
    float* l0 = (float*)Wqb;              // 65536 floats
    float* l1 = l0 + BATCH * NH * SEQ;    // 65536 floats

    cvt_bf16<<<dim3(8192), 256, 0, stream>>>(hs, Wq, Wk, Wv, Wo, Xb);
    qkv_rope<<<dim3(32, 24), 256, 0, stream>>>(Xb, Wqb, bq, Wkb, bk, Wvb, bv, qw, kw, vtw);
    attn_fwd<<<dim3(32, 16, 2), 256, 0, stream>>>(qw, kw, vtw, aw, p1, l0, l1);
    merge_norm<<<dim3(2048), 256, 0, stream>>>(aw, p1, l0, l1);
    out_proj<<<dim3(32, 8), 256, 0, stream>>>(aw, Wob, bo, out);
}